// Round 10
// baseline (364.495 us; speedup 1.0000x reference)
//
#include <hip/hip_runtime.h>

#define SEQ 2048

typedef short short8 __attribute__((ext_vector_type(8)));   // 8 bf16 (4 VGPRs)
typedef float floatx4 __attribute__((ext_vector_type(4)));  // 4 fp32 acc
typedef unsigned int uint2v __attribute__((ext_vector_type(2)));
typedef unsigned int uint4v __attribute__((ext_vector_type(4)));
typedef __fp16 f16x8 __attribute__((ext_vector_type(8)));   // 8 f16 (4 VGPRs) MFMA operand

static __device__ __forceinline__ unsigned short f2bf(float f) {
    unsigned int u = __builtin_bit_cast(unsigned int, f);
    u = (u + 0x7fffu + ((u >> 16) & 1u)) >> 16;   // RNE
    return (unsigned short)u;
}

#if __has_builtin(__builtin_amdgcn_cvt_pk_bf16_f32)
typedef __bf16 bf16x2 __attribute__((ext_vector_type(2)));
static __device__ __forceinline__ unsigned int pk_bf16(float a, float b) {
    bf16x2 v = __builtin_amdgcn_cvt_pk_bf16_f32(a, b);
    return __builtin_bit_cast(unsigned int, v);
}
#else
static __device__ __forceinline__ unsigned int pk_bf16(float a, float b) {
    return (unsigned int)f2bf(a) | ((unsigned int)f2bf(b) << 16);
}
#endif

// pack two fp32 -> two fp16 (RTZ); return raw u32
static __device__ __forceinline__ unsigned int pk_f16(float a, float b) {
    auto v = __builtin_amdgcn_cvt_pkrtz(a, b);    // __fp16 x2
    return __builtin_bit_cast(unsigned int, v);
}

// async global->LDS, 16 B/lane; LDS dest = wave-uniform base + lane*16
#define GLD16(gp, lp)                                                        \
    __builtin_amdgcn_global_load_lds(                                        \
        (const __attribute__((address_space(1))) unsigned int*)(gp),         \
        (__attribute__((address_space(3))) unsigned int*)(lp), 16, 0, 0)

// ---------------- merged prep: fp32->bf16 convert + weight transposes ----------------
__global__ void prep_kernel(const float4* __restrict__ xa, const float4* __restrict__ xb,
                            ushort4* __restrict__ oa, ushort4* __restrict__ ob, float sa,
                            const float* __restrict__ Wq, const float* __restrict__ Wkv,
                            const float* __restrict__ Wf,
                            unsigned short* __restrict__ oq, unsigned short* __restrict__ okv,
                            unsigned short* __restrict__ of_) {
    __shared__ float tile[32][33];
    int bx = blockIdx.x, tid = threadIdx.x;
    if (bx < 8192) {                       // cvt part (x_t scaled, x_s plain)
        int i = bx * 256 + tid;
        if (i < 1048576) {
            float4 v = xa[i];
            ushort4 o;
            o.x = f2bf(v.x * sa); o.y = f2bf(v.y * sa);
            o.z = f2bf(v.z * sa); o.w = f2bf(v.w * sa);
            oa[i] = o;
        } else {
            int j = i - 1048576;
            float4 v = xb[j];
            ushort4 o;
            o.x = f2bf(v.x); o.y = f2bf(v.y);
            o.z = f2bf(v.z); o.w = f2bf(v.w);
            ob[j] = o;
        }
        return;
    }
    int t2 = bx - 8192;                    // transpose part: W [K][N] fp32 -> [N][K] bf16
    const float* in; unsigned short* out; int N, t;
    if (t2 < 1024)      { in = Wq;  out = oq;  N = 1024; t = t2; }
    else if (t2 < 3072) { in = Wkv; out = okv; N = 2048; t = t2 - 1024; }
    else                { in = Wf;  out = of_; N = 1024; t = t2 - 3072; }
    int nb = N >> 5;
    int n0 = (t % nb) * 32, k0 = (t / nb) * 32;   // K = 1024 always
    int tx = tid & 31, ty = tid >> 5;
#pragma unroll
    for (int i = 0; i < 4; i++)
        tile[ty + i * 8][tx] = in[(size_t)(k0 + ty + i * 8) * N + n0 + tx];
    __syncthreads();
#pragma unroll
    for (int i = 0; i < 4; i++)
        out[(size_t)(n0 + ty + i * 8) * 1024 + k0 + tx] = f2bf(tile[tx][ty + i * 8]);
}

// ---------------- fused q+kv projection GEMM ----------------
// K written PRE-SWIZZLED bf16 (d ^ ((n&7)<<3)); V^T plain fp16 [bh][d][n].
// LDS-transposed epilogue -> 16B coalesced global stores (R7-proven).
__global__ __launch_bounds__(256, 3)
void gemm_qkv(const unsigned short* __restrict__ xt,
              const unsigned short* __restrict__ xs,
              const unsigned short* __restrict__ wq,
              const unsigned short* __restrict__ wkv,
              unsigned short* __restrict__ q_ws,
              unsigned short* __restrict__ k_ws,
              unsigned short* __restrict__ vt_ws) {
    __shared__ __align__(16) unsigned short smem_[16384];   // sA | sB, reused as scratch
    auto sA = (unsigned short(*)[64])smem_;
    auto sB = (unsigned short(*)[64])(smem_ + 8192);
    int tid = threadIdx.x, wave = tid >> 6, lane = tid & 63;
    int l15 = lane & 15, quad = lane >> 4;
    int cx = blockIdx.x;
    bool isq = cx < 8, isv = cx >= 16;
    const unsigned short* A  = isq ? xt : xs;
    const unsigned short* Bt = isq ? wq : wkv;
    int C0 = (isq ? cx : cx - 8) * 128;
    int R0 = blockIdx.y * 128;
    int wr = (wave >> 1) * 64, wc = (wave & 1) * 64;
    int srow = lane >> 3, scol = (lane & 7) * 8;   // staging: 8 rows / 1KB call

    floatx4 acc[4][4];
#pragma unroll
    for (int i = 0; i < 4; i++)
#pragma unroll
        for (int j = 0; j < 4; j++) acc[i][j] = (floatx4){0.f, 0.f, 0.f, 0.f};

    for (int kt = 0; kt < 16; kt++) {
        __syncthreads();                       // prev tile reads done
#pragma unroll
        for (int c = 0; c < 4; c++) {
            int rb = wave * 32 + c * 8;        // wave-uniform LDS dest row
            GLD16(&A [(size_t)(R0 + rb + srow) * 1024 + kt * 64 + scol], &sA[rb][0]);
            GLD16(&Bt[(size_t)(C0 + rb + srow) * 1024 + kt * 64 + scol], &sB[rb][0]);
        }
        __syncthreads();                       // vmcnt(0) drain + barrier
#pragma unroll
        for (int ks = 0; ks < 2; ks++) {
            short8 af[4], bf[4];
#pragma unroll
            for (int mt = 0; mt < 4; mt++)
                af[mt] = *(const short8*)&sA[wr + mt * 16 + l15][ks * 32 + quad * 8];
#pragma unroll
            for (int nt = 0; nt < 4; nt++)
                bf[nt] = *(const short8*)&sB[wc + nt * 16 + l15][ks * 32 + quad * 8];
#pragma unroll
            for (int mt = 0; mt < 4; mt++)
#pragma unroll
                for (int nt = 0; nt < 4; nt++)
                    acc[mt][nt] = __builtin_amdgcn_mfma_f32_16x16x32_bf16(af[mt], bf[nt], acc[mt][nt], 0, 0, 0);
        }
    }

    int b = R0 >> 11, n0 = R0 & 2047;      // 128-row tile stays within one batch
    __syncthreads();                       // LDS free for scratch

    if (!isv) {
        // q/k: scratch[row 0..127][col 0..127], then 16B stores (d-contiguous)
#pragma unroll
        for (int mt = 0; mt < 4; mt++)
#pragma unroll
            for (int nt = 0; nt < 4; nt++) {
                int col = wc + nt * 16 + l15;
#pragma unroll
                for (int r = 0; r < 4; r++)
                    smem_[(wr + mt * 16 + quad * 4 + r) * 128 + col] = f2bf(acc[mt][nt][r]);
            }
        __syncthreads();
        unsigned short* out = isq ? q_ws : k_ws;
#pragma unroll
        for (int i = 0; i < 8; i++) {
            int u = tid + i * 256;                 // 0..2047
            int row = u >> 4, colg = u & 15;
            int n = n0 + row;
            int gc = C0 + colg * 8;                // global col, 8-aligned
            int h = gc >> 6, d0 = gc & 63;
            int dd = isq ? d0 : ((((d0 >> 3) ^ (n & 7)) << 3));
            *(uint4v*)&out[((size_t)((b * 16 + h) * 2048 + n)) * 64 + dd] =
                *(const uint4v*)&smem_[row * 128 + colg * 8];
        }
    } else {
        // v: scratch[cc][n-local] with 8B-block XOR swizzle; 16B stores along n
#pragma unroll
        for (int mt = 0; mt < 4; mt++)
#pragma unroll
            for (int nt = 0; nt < 4; nt++) {
                int cc = wc + nt * 16 + l15;
                int nl4 = (wr + mt * 16 + quad * 4) >> 2;          // 8B block 0..31
                int sw = nl4 ^ ((cc & 3) << 1);
                uint2v pk;
                pk.x = pk_f16(acc[mt][nt][0], acc[mt][nt][1]);
                pk.y = pk_f16(acc[mt][nt][2], acc[mt][nt][3]);
                *(uint2v*)&smem_[cc * 128 + (sw << 2)] = pk;
            }
        __syncthreads();
        int cb = C0 - 1024;
#pragma unroll
        for (int i = 0; i < 8; i++) {
            int u = tid + i * 256;
            int cc = u >> 4, ng = u & 15;
            int sw0 = (2 * ng) ^ ((cc & 3) << 1);                  // even -> 16B aligned
            uint4v val = *(const uint4v*)&smem_[cc * 128 + (sw0 << 2)];
            int ccv = cb + cc, h = ccv >> 6, d = ccv & 63;
            *(uint4v*)&vt_ws[((size_t)((b * 16 + h) * 64 + d)) * 2048 + n0 + ng * 8] = val;
        }
    }
}

// ---------------- fuse GEMM ----------------
__global__ __launch_bounds__(256, 3)
void gemm_fuse(const unsigned short* __restrict__ A,
               const unsigned short* __restrict__ Bt,
               float* __restrict__ out, const float* __restrict__ bias) {
    __shared__ unsigned short sA[128][64];
    __shared__ unsigned short sB[64][64];
    int tid = threadIdx.x, wave = tid >> 6, lane = tid & 63;
    int l15 = lane & 15, quad = lane >> 4;
    int R0 = blockIdx.y * 128, C0 = blockIdx.x * 64;
    int wr = (wave >> 1) * 64, wc = (wave & 1) * 32;
    int srow = lane >> 3, scol = (lane & 7) * 8;

    floatx4 acc[4][2];
#pragma unroll
    for (int i = 0; i < 4; i++)
#pragma unroll
        for (int j = 0; j < 2; j++) acc[i][j] = (floatx4){0.f, 0.f, 0.f, 0.f};

    for (int kt = 0; kt < 16; kt++) {
        __syncthreads();
#pragma unroll
        for (int c = 0; c < 4; c++) {
            int rb = wave * 32 + c * 8;
            GLD16(&A[(size_t)(R0 + rb + srow) * 1024 + kt * 64 + scol], &sA[rb][0]);
        }
#pragma unroll
        for (int c = 0; c < 2; c++) {
            int rb = wave * 16 + c * 8;
            GLD16(&Bt[(size_t)(C0 + rb + srow) * 1024 + kt * 64 + scol], &sB[rb][0]);
        }
        __syncthreads();
#pragma unroll
        for (int ks = 0; ks < 2; ks++) {
            short8 af[4], bf[2];
#pragma unroll
            for (int mt = 0; mt < 4; mt++)
                af[mt] = *(const short8*)&sA[wr + mt * 16 + l15][ks * 32 + quad * 8];
#pragma unroll
            for (int nt = 0; nt < 2; nt++)
                bf[nt] = *(const short8*)&sB[wc + nt * 16 + l15][ks * 32 + quad * 8];
#pragma unroll
            for (int mt = 0; mt < 4; mt++)
#pragma unroll
                for (int nt = 0; nt < 2; nt++)
                    acc[mt][nt] = __builtin_amdgcn_mfma_f32_16x16x32_bf16(af[mt], bf[nt], acc[mt][nt], 0, 0, 0);
        }
    }

#pragma unroll
    for (int mt = 0; mt < 4; mt++) {
#pragma unroll
        for (int r = 0; r < 4; r++) {
            int row = R0 + wr + mt * 16 + quad * 4 + r;
#pragma unroll
            for (int nt = 0; nt < 2; nt++) {
                int col = C0 + wc + nt * 16 + l15;
                out[(size_t)row * 1024 + col] = acc[mt][nt][r] + bias[col];
            }
        }
    }
}

// ---------------- flash attention: QBLK=128, 8 waves (2 q-groups x 4 key-quarters) ----------------
// Round-10: staging throughput measured at a constant ~14-16 B/cyc/CU across
// R4/R6/R9 (barriers or not, TLP 2x or not) -> global_load_lds DMA path is the
// wall. Fix = REUSE: double QBLK to 128 rows/block -> grid halves to 512 ->
// total staged K/V bytes halve (512->256 MB). Per-wave state identical to R4's
// proven 104-VGPR shape (of[4][4]+qf[4][2]+pk), fits 128-cap of (512,4) ->
// 2 blocks/CU, 16 waves. Ring/barriers/vmcnt protocol unchanged from R9.
__global__ __launch_bounds__(512, 4)
void attn_kernel(const unsigned short* __restrict__ Q,   // [32][2048][64] bf16
                 const unsigned short* __restrict__ K,   // [32][2048][64] bf16, pre-swizzled
                 const unsigned short* __restrict__ Vt,  // [32][64][2048] fp16, plain
                 unsigned short* __restrict__ Aout) {    // [4096][1024] bf16
    __shared__ __align__(16) unsigned short smem[32768]; // 64KB: K[2 pair-slots][2 tiles] | V same
    __shared__ float lred[8][4][16];

    int tid = threadIdx.x, wave = tid >> 6, lane = tid & 63;
    int l15 = lane & 15, quad = lane >> 4;
    int kq = wave & 3;                   // key quarter
    int g  = wave >> 2;                  // q group (64 rows each)

    // XCD-chunked swizzle: id%8 = XCD; 64 logical per XCD -> 4 bh -> K/V L2-resident.
    int id = blockIdx.x;                 // 0..511
    int logical = (id & 7) * 64 + (id >> 3);
    int bh = logical >> 4, qt = logical & 15;
    int b = bh >> 4, h = bh & 15;
    int qr0 = qt * 128 + g * 64;         // this wave's 64 q-rows

    const unsigned short* Qp = Q + (size_t)bh * SEQ * 64;
    const unsigned short* Kp = K + (size_t)bh * SEQ * 64;
    const unsigned short* Vp = Vt + (size_t)bh * 64 * SEQ;

    int srow = lane >> 3, scol = (lane & 7) * 8;   // 8 rows / 1KB per DMA call
    int vscol = scol ^ (srow << 3);                // source-side V swizzle (d&7 == srow)
    int wk0 = kq * 16;                             // this wave's key rows in tile

    // stage one 64-key tile (K + V) at K-region ushort offset kb (V at +16384);
    // wave stages K rows [wave*8,+8) and V d-rows [wave*8,+8): 2 GLD16/wave
#define STAGE(t, kb)                                                          \
    {                                                                         \
        GLD16(&Kp[(size_t)((t) * 64 + wave * 8 + srow) * 64 + scol],          \
              &smem[(kb) + wave * 8 * 64]);                                   \
        GLD16(&Vp[(size_t)(wave * 8 + srow) * 2048 + (t) * 64 + vscol],       \
              &smem[16384 + (kb) + wave * 8 * 64]);                           \
    }

    // Q fragments: B-operand col=q=l15, k=ks*32+quad*8 -> direct global loads, in regs
    short8 qf[4][2];
#pragma unroll
    for (int nt = 0; nt < 4; nt++)
#pragma unroll
        for (int ks = 0; ks < 2; ks++)
            qf[nt][ks] = *(const short8*)&Qp[(size_t)(qr0 + nt * 16 + l15) * 64 + ks * 32 + quad * 8];

    STAGE(0, 0) STAGE(1, 4096) STAGE(2, 8192) STAGE(3, 12288)

    floatx4 of[4][4];   // O^T partial: [dt][nt], row=d=dt*16+quad*4+r, col=q=nt*16+l15
#pragma unroll
    for (int i = 0; i < 4; i++)
#pragma unroll
        for (int j = 0; j < 4; j++) of[i][j] = (floatx4){0.f, 0.f, 0.f, 0.f};
    floatx4 of_l[4];    // l accumulator per nt (ones-row MFMA; all regs = l[q])
#pragma unroll
    for (int i = 0; i < 4; i++) of_l[i] = (floatx4){0.f, 0.f, 0.f, 0.f};

    f16x8 vones;
#pragma unroll
    for (int i = 0; i < 8; i++) vones[i] = (__fp16)1.0f;

    int krow = wk0 + l15;
    int ksw = (l15 & 7) << 3;
    int kaddr0 = krow * 64 + ((quad * 8) ^ ksw);
    int kaddr1 = krow * 64 + ((32 + quad * 8) ^ ksw);
    int vcol = (wk0 + quad * 4) ^ ksw;             // LDS V row d: swizzled by d&7 == l15&7

    asm volatile("s_waitcnt vmcnt(0)" ::: "memory");   // Q + tiles 0..3 staged
    __syncthreads();

    // compute one PAIR of key-tiles: K slot base kb (tile A at kb, tile B at kb+4096)
    auto compute_pair = [&](int kb) {
        __builtin_amdgcn_s_setprio(1);
        uint2v pka[4], pkb[4];
        {   // tile A: S^T = K*Q^T, P = exp2(S) -> f16 pairs
            short8 kf0 = *(const short8*)&smem[kb + kaddr0];
            short8 kf1 = *(const short8*)&smem[kb + kaddr1];
#pragma unroll
            for (int nt = 0; nt < 4; nt++) {
                floatx4 z = (floatx4){0.f, 0.f, 0.f, 0.f};
                floatx4 s = __builtin_amdgcn_mfma_f32_16x16x32_bf16(kf0, qf[nt][0], z, 0, 0, 0);
                s = __builtin_amdgcn_mfma_f32_16x16x32_bf16(kf1, qf[nt][1], s, 0, 0, 0);
                pka[nt].x = pk_f16(__builtin_amdgcn_exp2f(s[0]), __builtin_amdgcn_exp2f(s[1]));
                pka[nt].y = pk_f16(__builtin_amdgcn_exp2f(s[2]), __builtin_amdgcn_exp2f(s[3]));
            }
        }
        {   // tile B
            short8 kf0 = *(const short8*)&smem[kb + 4096 + kaddr0];
            short8 kf1 = *(const short8*)&smem[kb + 4096 + kaddr1];
#pragma unroll
            for (int nt = 0; nt < 4; nt++) {
                floatx4 z = (floatx4){0.f, 0.f, 0.f, 0.f};
                floatx4 s = __builtin_amdgcn_mfma_f32_16x16x32_bf16(kf0, qf[nt][0], z, 0, 0, 0);
                s = __builtin_amdgcn_mfma_f32_16x16x32_bf16(kf1, qf[nt][1], s, 0, 0, 0);
                pkb[nt].x = pk_f16(__builtin_amdgcn_exp2f(s[0]), __builtin_amdgcn_exp2f(s[1]));
                pkb[nt].y = pk_f16(__builtin_amdgcn_exp2f(s[2]), __builtin_amdgcn_exp2f(s[3]));
            }
        }
        // PV with K=32: A = V^T frag (4 f16 per tile), B = P frag (pka | pkb)
#pragma unroll
        for (int dt = 0; dt < 4; dt++) {
            int vbase = 16384 + kb + (dt * 16 + l15) * 64 + vcol;
            uint2v va = *(const uint2v*)&smem[vbase];
            uint2v vb = *(const uint2v*)&smem[vbase + 4096];
            f16x8 vf = __builtin_bit_cast(f16x8, (uint4v){va.x, va.y, vb.x, vb.y});
#pragma unroll
            for (int nt = 0; nt < 4; nt++) {
                f16x8 pf = __builtin_bit_cast(f16x8, (uint4v){pka[nt].x, pka[nt].y, pkb[nt].x, pkb[nt].y});
                of[dt][nt] = __builtin_amdgcn_mfma_f32_16x16x32_f16(vf, pf, of[dt][nt], 0, 0, 0);
            }
        }
        // l[q] += sum_key P: ones-row MFMA (k-sum spans quads -> no shuffles)
#pragma unroll
        for (int nt = 0; nt < 4; nt++) {
            f16x8 pf = __builtin_bit_cast(f16x8, (uint4v){pka[nt].x, pka[nt].y, pkb[nt].x, pkb[nt].y});
            of_l[nt] = __builtin_amdgcn_mfma_f32_16x16x32_f16(vones, pf, of_l[nt], 0, 0, 0);
        }
        __builtin_amdgcn_s_setprio(0);
    };

    // steady state: 16 pairs; stage pair p+2 while computing pair p; vmcnt(4)
    // waits pair p+1 (4 GLD16/wave/pair; never drains to 0 in the main loop)
#pragma unroll 2
    for (int p = 0; p < 14; p++) {
        int kb = (p & 1) * 8192;
        compute_pair(kb);
        __builtin_amdgcn_sched_barrier(0);
        asm volatile("s_barrier" ::: "memory");          // all reads of this slot done
        STAGE(2 * p + 4, kb)                             // restage slot with pair p+2
        STAGE(2 * p + 5, kb + 4096)
        asm volatile("s_waitcnt vmcnt(4)" ::: "memory"); // pair p+1 landed
        asm volatile("s_barrier" ::: "memory");          // cross-wave visibility
        __builtin_amdgcn_sched_barrier(0);
    }
    // tail: pair 14 (slot 0), pair 15 (slot 1); pair-15 DMAs still in flight at entry
    compute_pair(0);
    asm volatile("s_waitcnt vmcnt(0)" ::: "memory");
    asm volatile("s_barrier" ::: "memory");
    compute_pair(8192);
#undef STAGE

    // ---- epilogue: l (quad-reduced by ones-MFMA) + cross-kq O reduction via LDS ----
    if (quad == 0) {
#pragma unroll
        for (int nt = 0; nt < 4; nt++) lred[wave][nt][l15] = of_l[nt][0];
    }
    __syncthreads();   // all tile reads done before smem is reused as reduction scratch

    float* red = (float*)smem;   // 16384 floats; slot(c,g,kq) = ((c*2+g)*4+kq)*1024
    int myc = kq >> 1, nt0 = (kq & 1) * 2;

    // round 1: ship of[0] (c=0) and of[1] (c=1); store dt = myc
#pragma unroll
    for (int nt = 0; nt < 4; nt++) {
        *(floatx4*)&red[((0 * 2 + g) * 4 + kq) * 1024 + nt * 256 + lane * 4] = of[0][nt];
        *(floatx4*)&red[((1 * 2 + g) * 4 + kq) * 1024 + nt * 256 + lane * 4] = of[1][nt];
    }
    __syncthreads();
#pragma unroll
    for (int j = 0; j < 2; j++) {
        int nt = nt0 + j;
        floatx4 s = (floatx4){0.f, 0.f, 0.f, 0.f};
#pragma unroll
        for (int k4 = 0; k4 < 4; k4++)
            s += *(const floatx4*)&red[((myc * 2 + g) * 4 + k4) * 1024 + nt * 256 + lane * 4];
        float lt = lred[g * 4 + 0][nt][l15] + lred[g * 4 + 1][nt][l15] +
                   lred[g * 4 + 2][nt][l15] + lred[g * 4 + 3][nt][l15];
        float inv = 1.f / lt;
        uint2v o;
        o.x = pk_bf16(s[0] * inv, s[1] * inv);
        o.y = pk_bf16(s[2] * inv, s[3] * inv);
        *(uint2v*)&Aout[(size_t)(b * SEQ + qr0 + nt * 16 + l15) * 1024 + h * 64 + myc * 16 + quad * 4] = o;
    }
    __syncthreads();
    // round 2: ship of[2] (c=0) and of[3] (c=1); store dt = myc + 2
#pragma unroll
    for (int nt = 0; nt < 4; nt++) {
        *(floatx4*)&red[((0 * 2 + g) * 4 + kq) * 1024 + nt * 256 + lane * 4] = of[2][nt];
        *(floatx4*)&red[((1 * 2 + g) * 4 + kq) * 1024 + nt * 256 + lane * 4] = of[3][nt];
    }
    __syncthreads();
#pragma unroll
    for (int j = 0; j < 2; j++) {
        int nt = nt0 + j;
        floatx4 s = (floatx4){0.f, 0.f, 0.f, 0.f};
#pragma unroll
        for (int k4 = 0; k4 < 4; k4++)
            s += *(const floatx4*)&red[((myc * 2 + g) * 4 + k4) * 1024 + nt * 256 + lane * 4];
        float lt = lred[g * 4 + 0][nt][l15] + lred[g * 4 + 1][nt][l15] +
                   lred[g * 4 + 2][nt][l15] + lred[g * 4 + 3][nt][l15];
        float inv = 1.f / lt;
        uint2v o;
        o.x = pk_bf16(s[0] * inv, s[1] * inv);
        o.y = pk_bf16(s[2] * inv, s[3] * inv);
        *(uint2v*)&Aout[(size_t)(b * SEQ + qr0 + nt * 16 + l15) * 1024 + h * 64 + (myc + 2) * 16 + quad * 4] = o;
    }
}

extern "C" void kernel_launch(void* const* d_in, const int* in_sizes, int n_in,
                              void* d_out, int out_size, void* d_ws, size_t ws_size,
                              hipStream_t stream) {
    const float* x_t  = (const float*)d_in[0];
    const float* x_s  = (const float*)d_in[1];
    const float* W_q  = (const float*)d_in[2];
    const float* W_kv = (const float*)d_in[3];
    const float* W_f  = (const float*)d_in[4];
    const float* b_f  = (const float*)d_in[5];
    float* out = (float*)d_out;

    char* ws = (char*)d_ws;
    const size_t MB = 1u << 20;
    unsigned short* xt_bf = (unsigned short*)(ws);            // 8 MB
    unsigned short* xs_bf = (unsigned short*)(ws + 8 * MB);   // 8 MB
    unsigned short* wq_t  = (unsigned short*)(ws + 16 * MB);  // 2 MB
    unsigned short* wkv_t = (unsigned short*)(ws + 18 * MB);  // 4 MB
    unsigned short* wf_t  = (unsigned short*)(ws + 22 * MB);  // 2 MB
    unsigned short* q_ws  = (unsigned short*)(ws + 24 * MB);  // 8 MB
    unsigned short* k_ws  = (unsigned short*)(ws + 32 * MB);  // 8 MB (pre-swizzled)
    unsigned short* vt_ws = (unsigned short*)(ws + 40 * MB);  // 8 MB (plain fp16)
    unsigned short* a_ws  = (unsigned short*)(ws + 48 * MB);  // 8 MB (total 56 MB)

    // SCALE * log2(e) folded into x_t so attention logits are in log2 domain
    prep_kernel<<<12288, 256, 0, stream>>>((const float4*)x_t, (const float4*)x_s,
                                           (ushort4*)xt_bf, (ushort4*)xs_bf,
                                           0.125f * 1.44269504088896340736f,
                                           W_q, W_kv, W_f, wq_t, wkv_t, wf_t);

    gemm_qkv<<<dim3(24, 32), 256, 0, stream>>>(xt_bf, xs_bf, wq_t, wkv_t, q_ws, k_ws, vt_ws);
    attn_kernel<<<512, 512, 0, stream>>>(q_ws, k_ws, vt_ws, a_ws);
    gemm_fuse<<<dim3(16, 32), 256, 0, stream>>>(a_ws, wf_t, out, b_f);
}

// Round 11
// 191.119 us; speedup vs baseline: 1.9072x; 1.9072x over previous
//
#include <hip/hip_runtime.h>

#define SEQ 2048

typedef short short8 __attribute__((ext_vector_type(8)));   // 8 bf16 (4 VGPRs)
typedef float floatx4 __attribute__((ext_vector_type(4)));  // 4 fp32 acc
typedef unsigned int uint2v __attribute__((ext_vector_type(2)));
typedef unsigned int uint4v __attribute__((ext_vector_type(4)));
typedef __fp16 f16x8 __attribute__((ext_vector_type(8)));   // 8 f16 (4 VGPRs) MFMA operand

static __device__ __forceinline__ unsigned short f2bf(float f) {
    unsigned int u = __builtin_bit_cast(unsigned int, f);
    u = (u + 0x7fffu + ((u >> 16) & 1u)) >> 16;   // RNE
    return (unsigned short)u;
}

#if __has_builtin(__builtin_amdgcn_cvt_pk_bf16_f32)
typedef __bf16 bf16x2 __attribute__((ext_vector_type(2)));
static __device__ __forceinline__ unsigned int pk_bf16(float a, float b) {
    bf16x2 v = __builtin_amdgcn_cvt_pk_bf16_f32(a, b);
    return __builtin_bit_cast(unsigned int, v);
}
#else
static __device__ __forceinline__ unsigned int pk_bf16(float a, float b) {
    return (unsigned int)f2bf(a) | ((unsigned int)f2bf(b) << 16);
}
#endif

// pack two fp32 -> two fp16 (RTZ); return raw u32
static __device__ __forceinline__ unsigned int pk_f16(float a, float b) {
    auto v = __builtin_amdgcn_cvt_pkrtz(a, b);    // __fp16 x2
    return __builtin_bit_cast(unsigned int, v);
}

// async global->LDS, 16 B/lane; LDS dest = wave-uniform base + lane*16
#define GLD16(gp, lp)                                                        \
    __builtin_amdgcn_global_load_lds(                                        \
        (const __attribute__((address_space(1))) unsigned int*)(gp),         \
        (__attribute__((address_space(3))) unsigned int*)(lp), 16, 0, 0)

// ---------------- merged prep: fp32->bf16 convert + weight transposes ----------------
__global__ void prep_kernel(const float4* __restrict__ xa, const float4* __restrict__ xb,
                            ushort4* __restrict__ oa, ushort4* __restrict__ ob, float sa,
                            const float* __restrict__ Wq, const float* __restrict__ Wkv,
                            const float* __restrict__ Wf,
                            unsigned short* __restrict__ oq, unsigned short* __restrict__ okv,
                            unsigned short* __restrict__ of_) {
    __shared__ float tile[32][33];
    int bx = blockIdx.x, tid = threadIdx.x;
    if (bx < 8192) {                       // cvt part (x_t scaled, x_s plain)
        int i = bx * 256 + tid;
        if (i < 1048576) {
            float4 v = xa[i];
            ushort4 o;
            o.x = f2bf(v.x * sa); o.y = f2bf(v.y * sa);
            o.z = f2bf(v.z * sa); o.w = f2bf(v.w * sa);
            oa[i] = o;
        } else {
            int j = i - 1048576;
            float4 v = xb[j];
            ushort4 o;
            o.x = f2bf(v.x); o.y = f2bf(v.y);
            o.z = f2bf(v.z); o.w = f2bf(v.w);
            ob[j] = o;
        }
        return;
    }
    int t2 = bx - 8192;                    // transpose part: W [K][N] fp32 -> [N][K] bf16
    const float* in; unsigned short* out; int N, t;
    if (t2 < 1024)      { in = Wq;  out = oq;  N = 1024; t = t2; }
    else if (t2 < 3072) { in = Wkv; out = okv; N = 2048; t = t2 - 1024; }
    else                { in = Wf;  out = of_; N = 1024; t = t2 - 3072; }
    int nb = N >> 5;
    int n0 = (t % nb) * 32, k0 = (t / nb) * 32;   // K = 1024 always
    int tx = tid & 31, ty = tid >> 5;
#pragma unroll
    for (int i = 0; i < 4; i++)
        tile[ty + i * 8][tx] = in[(size_t)(k0 + ty + i * 8) * N + n0 + tx];
    __syncthreads();
#pragma unroll
    for (int i = 0; i < 4; i++)
        out[(size_t)(n0 + ty + i * 8) * 1024 + k0 + tx] = f2bf(tile[tx][ty + i * 8]);
}

// ---------------- fused q+kv projection GEMM ----------------
// K written PRE-SWIZZLED bf16 (d ^ ((n&7)<<3)); V^T plain fp16 [bh][d][n].
// LDS-transposed epilogue -> 16B coalesced global stores (R7-proven).
__global__ __launch_bounds__(256, 3)
void gemm_qkv(const unsigned short* __restrict__ xt,
              const unsigned short* __restrict__ xs,
              const unsigned short* __restrict__ wq,
              const unsigned short* __restrict__ wkv,
              unsigned short* __restrict__ q_ws,
              unsigned short* __restrict__ k_ws,
              unsigned short* __restrict__ vt_ws) {
    __shared__ __align__(16) unsigned short smem_[16384];   // sA | sB, reused as scratch
    auto sA = (unsigned short(*)[64])smem_;
    auto sB = (unsigned short(*)[64])(smem_ + 8192);
    int tid = threadIdx.x, wave = tid >> 6, lane = tid & 63;
    int l15 = lane & 15, quad = lane >> 4;
    int cx = blockIdx.x;
    bool isq = cx < 8, isv = cx >= 16;
    const unsigned short* A  = isq ? xt : xs;
    const unsigned short* Bt = isq ? wq : wkv;
    int C0 = (isq ? cx : cx - 8) * 128;
    int R0 = blockIdx.y * 128;
    int wr = (wave >> 1) * 64, wc = (wave & 1) * 64;
    int srow = lane >> 3, scol = (lane & 7) * 8;   // staging: 8 rows / 1KB call

    floatx4 acc[4][4];
#pragma unroll
    for (int i = 0; i < 4; i++)
#pragma unroll
        for (int j = 0; j < 4; j++) acc[i][j] = (floatx4){0.f, 0.f, 0.f, 0.f};

    for (int kt = 0; kt < 16; kt++) {
        __syncthreads();                       // prev tile reads done
#pragma unroll
        for (int c = 0; c < 4; c++) {
            int rb = wave * 32 + c * 8;        // wave-uniform LDS dest row
            GLD16(&A [(size_t)(R0 + rb + srow) * 1024 + kt * 64 + scol], &sA[rb][0]);
            GLD16(&Bt[(size_t)(C0 + rb + srow) * 1024 + kt * 64 + scol], &sB[rb][0]);
        }
        __syncthreads();                       // vmcnt(0) drain + barrier
#pragma unroll
        for (int ks = 0; ks < 2; ks++) {
            short8 af[4], bf[4];
#pragma unroll
            for (int mt = 0; mt < 4; mt++)
                af[mt] = *(const short8*)&sA[wr + mt * 16 + l15][ks * 32 + quad * 8];
#pragma unroll
            for (int nt = 0; nt < 4; nt++)
                bf[nt] = *(const short8*)&sB[wc + nt * 16 + l15][ks * 32 + quad * 8];
#pragma unroll
            for (int mt = 0; mt < 4; mt++)
#pragma unroll
                for (int nt = 0; nt < 4; nt++)
                    acc[mt][nt] = __builtin_amdgcn_mfma_f32_16x16x32_bf16(af[mt], bf[nt], acc[mt][nt], 0, 0, 0);
        }
    }

    int b = R0 >> 11, n0 = R0 & 2047;      // 128-row tile stays within one batch
    __syncthreads();                       // LDS free for scratch

    if (!isv) {
        // q/k: scratch[row 0..127][col 0..127], then 16B stores (d-contiguous)
#pragma unroll
        for (int mt = 0; mt < 4; mt++)
#pragma unroll
            for (int nt = 0; nt < 4; nt++) {
                int col = wc + nt * 16 + l15;
#pragma unroll
                for (int r = 0; r < 4; r++)
                    smem_[(wr + mt * 16 + quad * 4 + r) * 128 + col] = f2bf(acc[mt][nt][r]);
            }
        __syncthreads();
        unsigned short* out = isq ? q_ws : k_ws;
#pragma unroll
        for (int i = 0; i < 8; i++) {
            int u = tid + i * 256;                 // 0..2047
            int row = u >> 4, colg = u & 15;
            int n = n0 + row;
            int gc = C0 + colg * 8;                // global col, 8-aligned
            int h = gc >> 6, d0 = gc & 63;
            int dd = isq ? d0 : ((((d0 >> 3) ^ (n & 7)) << 3));
            *(uint4v*)&out[((size_t)((b * 16 + h) * 2048 + n)) * 64 + dd] =
                *(const uint4v*)&smem_[row * 128 + colg * 8];
        }
    } else {
        // v: scratch[cc][n-local] with 8B-block XOR swizzle; 16B stores along n
#pragma unroll
        for (int mt = 0; mt < 4; mt++)
#pragma unroll
            for (int nt = 0; nt < 4; nt++) {
                int cc = wc + nt * 16 + l15;
                int nl4 = (wr + mt * 16 + quad * 4) >> 2;          // 8B block 0..31
                int sw = nl4 ^ ((cc & 3) << 1);
                uint2v pk;
                pk.x = pk_f16(acc[mt][nt][0], acc[mt][nt][1]);
                pk.y = pk_f16(acc[mt][nt][2], acc[mt][nt][3]);
                *(uint2v*)&smem_[cc * 128 + (sw << 2)] = pk;
            }
        __syncthreads();
        int cb = C0 - 1024;
#pragma unroll
        for (int i = 0; i < 8; i++) {
            int u = tid + i * 256;
            int cc = u >> 4, ng = u & 15;
            int sw0 = (2 * ng) ^ ((cc & 3) << 1);                  // even -> 16B aligned
            uint4v val = *(const uint4v*)&smem_[cc * 128 + (sw0 << 2)];
            int ccv = cb + cc, h = ccv >> 6, d = ccv & 63;
            *(uint4v*)&vt_ws[((size_t)((b * 16 + h) * 64 + d)) * 2048 + n0 + ng * 8] = val;
        }
    }
}

// ---------------- fuse GEMM ----------------
__global__ __launch_bounds__(256, 3)
void gemm_fuse(const unsigned short* __restrict__ A,
               const unsigned short* __restrict__ Bt,
               float* __restrict__ out, const float* __restrict__ bias) {
    __shared__ unsigned short sA[128][64];
    __shared__ unsigned short sB[64][64];
    int tid = threadIdx.x, wave = tid >> 6, lane = tid & 63;
    int l15 = lane & 15, quad = lane >> 4;
    int R0 = blockIdx.y * 128, C0 = blockIdx.x * 64;
    int wr = (wave >> 1) * 64, wc = (wave & 1) * 32;
    int srow = lane >> 3, scol = (lane & 7) * 8;

    floatx4 acc[4][2];
#pragma unroll
    for (int i = 0; i < 4; i++)
#pragma unroll
        for (int j = 0; j < 2; j++) acc[i][j] = (floatx4){0.f, 0.f, 0.f, 0.f};

    for (int kt = 0; kt < 16; kt++) {
        __syncthreads();
#pragma unroll
        for (int c = 0; c < 4; c++) {
            int rb = wave * 32 + c * 8;
            GLD16(&A[(size_t)(R0 + rb + srow) * 1024 + kt * 64 + scol], &sA[rb][0]);
        }
#pragma unroll
        for (int c = 0; c < 2; c++) {
            int rb = wave * 16 + c * 8;
            GLD16(&Bt[(size_t)(C0 + rb + srow) * 1024 + kt * 64 + scol], &sB[rb][0]);
        }
        __syncthreads();
#pragma unroll
        for (int ks = 0; ks < 2; ks++) {
            short8 af[4], bf[2];
#pragma unroll
            for (int mt = 0; mt < 4; mt++)
                af[mt] = *(const short8*)&sA[wr + mt * 16 + l15][ks * 32 + quad * 8];
#pragma unroll
            for (int nt = 0; nt < 2; nt++)
                bf[nt] = *(const short8*)&sB[wc + nt * 16 + l15][ks * 32 + quad * 8];
#pragma unroll
            for (int mt = 0; mt < 4; mt++)
#pragma unroll
                for (int nt = 0; nt < 2; nt++)
                    acc[mt][nt] = __builtin_amdgcn_mfma_f32_16x16x32_bf16(af[mt], bf[nt], acc[mt][nt], 0, 0, 0);
        }
    }

#pragma unroll
    for (int mt = 0; mt < 4; mt++) {
#pragma unroll
        for (int r = 0; r < 4; r++) {
            int row = R0 + wr + mt * 16 + quad * 4 + r;
#pragma unroll
            for (int nt = 0; nt < 2; nt++) {
                int col = C0 + wc + nt * 16 + l15;
                out[(size_t)row * 1024 + col] = acc[mt][nt][r] + bias[col];
            }
        }
    }
}

// ---------------- flash attention: QBLK=128, 8 waves = 4 q-groups x 2 key-halves ----------------
// Round-11: halve staged DMA bytes (the measured ~16 B/cyc/CU wall) WITHOUT
// inflating per-wave state (R10's spill). Wave (g,kh): 32 q-rows x 32 keys.
// With 32 keys/wave, K=32 PV pairs WITHIN one tile: chunk0 (keys wk0..+15) ->
// frag elems 0-3, chunk1 (wk0+16..+31) -> elems 4-7 (valid: MFMA dot products
// are permutation-invariant when V-frag and P-frag use the same key<->element
// map, each key once). State: of[4][2]+qf[2][2]+2x2 P-chunks ~= R9+24 regs,
// fits (512,4) cap 128 -> 2 blocks/CU. Ring/vmcnt/barriers = R9 verbatim.
// Grid 512 (32 bh x 16 q-tiles of 128 rows): staged K/V 512->256 MB.
__global__ __launch_bounds__(512, 4)
void attn_kernel(const unsigned short* __restrict__ Q,   // [32][2048][64] bf16
                 const unsigned short* __restrict__ K,   // [32][2048][64] bf16, pre-swizzled
                 const unsigned short* __restrict__ Vt,  // [32][64][2048] fp16, plain
                 unsigned short* __restrict__ Aout) {    // [4096][1024] bf16
    __shared__ __align__(16) unsigned short smem[32768]; // 64KB: K[2 pair-slots][2 tiles] | V same
    __shared__ float lred[8][2][16];

    int tid = threadIdx.x, wave = tid >> 6, lane = tid & 63;
    int l15 = lane & 15, quad = lane >> 4;
    int g  = wave >> 1;                  // q group (32 rows each, 4 groups)
    int kh = wave & 1;                   // key half (32 keys each)

    // XCD-chunked swizzle: id%8 = XCD; 64 logical per XCD -> 4 bh -> K/V L2-resident.
    int id = blockIdx.x;                 // 0..511
    int logical = (id & 7) * 64 + (id >> 3);
    int bh = logical >> 4, qt = logical & 15;
    int b = bh >> 4, h = bh & 15;
    int qr0 = qt * 128 + g * 32;         // this wave's 32 q-rows

    const unsigned short* Qp = Q + (size_t)bh * SEQ * 64;
    const unsigned short* Kp = K + (size_t)bh * SEQ * 64;
    const unsigned short* Vp = Vt + (size_t)bh * 64 * SEQ;

    int srow = lane >> 3, scol = (lane & 7) * 8;   // 8 rows / 1KB per DMA call
    int vscol = scol ^ (srow << 3);                // source-side V swizzle (d&7 == srow)
    int wk0 = kh * 32;                             // this wave's 32 keys in tile

    // stage one 64-key tile (K + V) at K-region ushort offset kb (V at +16384);
    // wave stages K rows [wave*8,+8) and V d-rows [wave*8,+8): 2 GLD16/wave
#define STAGE(t, kb)                                                          \
    {                                                                         \
        GLD16(&Kp[(size_t)((t) * 64 + wave * 8 + srow) * 64 + scol],          \
              &smem[(kb) + wave * 8 * 64]);                                   \
        GLD16(&Vp[(size_t)(wave * 8 + srow) * 2048 + (t) * 64 + vscol],       \
              &smem[16384 + (kb) + wave * 8 * 64]);                           \
    }

    // Q fragments: B-operand col=q=l15, k=ks*32+quad*8 -> direct global loads, in regs
    short8 qf[2][2];
#pragma unroll
    for (int nt = 0; nt < 2; nt++)
#pragma unroll
        for (int ks = 0; ks < 2; ks++)
            qf[nt][ks] = *(const short8*)&Qp[(size_t)(qr0 + nt * 16 + l15) * 64 + ks * 32 + quad * 8];

    STAGE(0, 0) STAGE(1, 4096) STAGE(2, 8192) STAGE(3, 12288)

    floatx4 of[4][2];   // O^T partial: [dt][nt], row=d=dt*16+quad*4+r, col=q=nt*16+l15
#pragma unroll
    for (int i = 0; i < 4; i++)
#pragma unroll
        for (int j = 0; j < 2; j++) of[i][j] = (floatx4){0.f, 0.f, 0.f, 0.f};
    floatx4 of_l[2];    // l accumulator per nt (ones-row MFMA; all regs = l[q])
#pragma unroll
    for (int i = 0; i < 2; i++) of_l[i] = (floatx4){0.f, 0.f, 0.f, 0.f};

    f16x8 vones;
#pragma unroll
    for (int i = 0; i < 8; i++) vones[i] = (__fp16)1.0f;

    // K read addressing (tile-local): chunk0 rows wk0+l15, chunk1 rows wk0+16+l15
    int ksw = (l15 & 7) << 3;
    int ka0 = (wk0 + l15) * 64 + ((quad * 8) ^ ksw);
    int ka1 = (wk0 + l15) * 64 + ((32 + quad * 8) ^ ksw);
    int ka2 = (wk0 + 16 + l15) * 64 + ((quad * 8) ^ ksw);
    int ka3 = (wk0 + 16 + l15) * 64 + ((32 + quad * 8) ^ ksw);
    // V cols (LDS row d: swizzle by d&7 == l15&7): chunk0 / chunk1 key offsets
    int vcol0 = (wk0 + quad * 4) ^ ksw;
    int vcol1 = (wk0 + 16 + quad * 4) ^ ksw;

    asm volatile("s_waitcnt vmcnt(0)" ::: "memory");   // Q + tiles 0..3 staged
    __syncthreads();

    // compute ONE 64-key tile at ushort offset tb: S over 2 key-chunks -> P in
    // regs -> K=32 PV within the tile (chunk0 = frag elems 0-3, chunk1 = 4-7)
    auto compute_tile = [&](int tb) {
        uint2v p0[2], p1[2];
        {   // chunk 0: keys wk0..+15
            short8 kf0 = *(const short8*)&smem[tb + ka0];
            short8 kf1 = *(const short8*)&smem[tb + ka1];
#pragma unroll
            for (int nt = 0; nt < 2; nt++) {
                floatx4 z = (floatx4){0.f, 0.f, 0.f, 0.f};
                floatx4 s = __builtin_amdgcn_mfma_f32_16x16x32_bf16(kf0, qf[nt][0], z, 0, 0, 0);
                s = __builtin_amdgcn_mfma_f32_16x16x32_bf16(kf1, qf[nt][1], s, 0, 0, 0);
                p0[nt].x = pk_f16(__builtin_amdgcn_exp2f(s[0]), __builtin_amdgcn_exp2f(s[1]));
                p0[nt].y = pk_f16(__builtin_amdgcn_exp2f(s[2]), __builtin_amdgcn_exp2f(s[3]));
            }
        }
        {   // chunk 1: keys wk0+16..+31
            short8 kf0 = *(const short8*)&smem[tb + ka2];
            short8 kf1 = *(const short8*)&smem[tb + ka3];
#pragma unroll
            for (int nt = 0; nt < 2; nt++) {
                floatx4 z = (floatx4){0.f, 0.f, 0.f, 0.f};
                floatx4 s = __builtin_amdgcn_mfma_f32_16x16x32_bf16(kf0, qf[nt][0], z, 0, 0, 0);
                s = __builtin_amdgcn_mfma_f32_16x16x32_bf16(kf1, qf[nt][1], s, 0, 0, 0);
                p1[nt].x = pk_f16(__builtin_amdgcn_exp2f(s[0]), __builtin_amdgcn_exp2f(s[1]));
                p1[nt].y = pk_f16(__builtin_amdgcn_exp2f(s[2]), __builtin_amdgcn_exp2f(s[3]));
            }
        }
        // PV K=32 within tile: A = V^T frag (chunk0 4 f16 | chunk1 4 f16)
#pragma unroll
        for (int dt = 0; dt < 4; dt++) {
            int vbase = 16384 + tb + (dt * 16 + l15) * 64;
            uint2v va = *(const uint2v*)&smem[vbase + vcol0];
            uint2v vb = *(const uint2v*)&smem[vbase + vcol1];
            f16x8 vf = __builtin_bit_cast(f16x8, (uint4v){va.x, va.y, vb.x, vb.y});
#pragma unroll
            for (int nt = 0; nt < 2; nt++) {
                f16x8 pf = __builtin_bit_cast(f16x8, (uint4v){p0[nt].x, p0[nt].y, p1[nt].x, p1[nt].y});
                of[dt][nt] = __builtin_amdgcn_mfma_f32_16x16x32_f16(vf, pf, of[dt][nt], 0, 0, 0);
            }
        }
        // l[q] += sum_key P: ones-row MFMA (k-sum spans quads -> no shuffles)
#pragma unroll
        for (int nt = 0; nt < 2; nt++) {
            f16x8 pf = __builtin_bit_cast(f16x8, (uint4v){p0[nt].x, p0[nt].y, p1[nt].x, p1[nt].y});
            of_l[nt] = __builtin_amdgcn_mfma_f32_16x16x32_f16(vones, pf, of_l[nt], 0, 0, 0);
        }
    };
    auto compute_pair = [&](int kb) {
        __builtin_amdgcn_s_setprio(1);
        compute_tile(kb);
        compute_tile(kb + 4096);
        __builtin_amdgcn_s_setprio(0);
    };

    // steady state: 16 pairs; stage pair p+2 while computing pair p; vmcnt(4)
    // waits pair p+1 (4 GLD16/wave/pair; never drains to 0 in the main loop)
#pragma unroll 2
    for (int p = 0; p < 14; p++) {
        int kb = (p & 1) * 8192;
        compute_pair(kb);
        __builtin_amdgcn_sched_barrier(0);
        asm volatile("s_barrier" ::: "memory");          // all reads of this slot done
        STAGE(2 * p + 4, kb)                             // restage slot with pair p+2
        STAGE(2 * p + 5, kb + 4096)
        asm volatile("s_waitcnt vmcnt(4)" ::: "memory"); // pair p+1 landed
        asm volatile("s_barrier" ::: "memory");          // cross-wave visibility
        __builtin_amdgcn_sched_barrier(0);
    }
    // tail: pair 14 (slot 0), pair 15 (slot 1); pair-15 DMAs still in flight at entry
    compute_pair(0);
    asm volatile("s_waitcnt vmcnt(0)" ::: "memory");
    asm volatile("s_barrier" ::: "memory");
    compute_pair(8192);
#undef STAGE

    // ---- epilogue: l (quad-reduced by ones-MFMA) + cross-kh O reduction via LDS ----
    if (quad == 0) {
#pragma unroll
        for (int nt = 0; nt < 2; nt++) lred[wave][nt][l15] = of_l[nt][0];
    }
    __syncthreads();   // all tile reads done before smem is reused as reduction scratch

    float* red = (float*)smem;   // 16384 floats = 64KB: slot(w,dt,nt) = ((w*4+dt)*2+nt)*256

    // single full dump: 8 waves x of[4][2] (8 KB each) = 64 KB exactly
#pragma unroll
    for (int dt = 0; dt < 4; dt++)
#pragma unroll
        for (int nt = 0; nt < 2; nt++)
            *(floatx4*)&red[((wave * 4 + dt) * 2 + nt) * 256 + lane * 4] = of[dt][nt];
    __syncthreads();

    // wave (g,kh) reduces dt in {kh*2, kh*2+1} for its q-group over the 2 kh-waves
#pragma unroll
    for (int dd = 0; dd < 2; dd++) {
        int dt = kh * 2 + dd;
#pragma unroll
        for (int nt = 0; nt < 2; nt++) {
            floatx4 s = *(const floatx4*)&red[(((g * 2 + 0) * 4 + dt) * 2 + nt) * 256 + lane * 4]
                      + *(const floatx4*)&red[(((g * 2 + 1) * 4 + dt) * 2 + nt) * 256 + lane * 4];
            float lt = lred[g * 2 + 0][nt][l15] + lred[g * 2 + 1][nt][l15];
            float inv = 1.f / lt;
            uint2v o;
            o.x = pk_bf16(s[0] * inv, s[1] * inv);
            o.y = pk_bf16(s[2] * inv, s[3] * inv);
            *(uint2v*)&Aout[(size_t)(b * SEQ + qr0 + nt * 16 + l15) * 1024 + h * 64 + dt * 16 + quad * 4] = o;
        }
    }
}

extern "C" void kernel_launch(void* const* d_in, const int* in_sizes, int n_in,
                              void* d_out, int out_size, void* d_ws, size_t ws_size,
                              hipStream_t stream) {
    const float* x_t  = (const float*)d_in[0];
    const float* x_s  = (const float*)d_in[1];
    const float* W_q  = (const float*)d_in[2];
    const float* W_kv = (const float*)d_in[3];
    const float* W_f  = (const float*)d_in[4];
    const float* b_f  = (const float*)d_in[5];
    float* out = (float*)d_out;

    char* ws = (char*)d_ws;
    const size_t MB = 1u << 20;
    unsigned short* xt_bf = (unsigned short*)(ws);            // 8 MB
    unsigned short* xs_bf = (unsigned short*)(ws + 8 * MB);   // 8 MB
    unsigned short* wq_t  = (unsigned short*)(ws + 16 * MB);  // 2 MB
    unsigned short* wkv_t = (unsigned short*)(ws + 18 * MB);  // 4 MB
    unsigned short* wf_t  = (unsigned short*)(ws + 22 * MB);  // 2 MB
    unsigned short* q_ws  = (unsigned short*)(ws + 24 * MB);  // 8 MB
    unsigned short* k_ws  = (unsigned short*)(ws + 32 * MB);  // 8 MB (pre-swizzled)
    unsigned short* vt_ws = (unsigned short*)(ws + 40 * MB);  // 8 MB (plain fp16)
    unsigned short* a_ws  = (unsigned short*)(ws + 48 * MB);  // 8 MB (total 56 MB)

    // SCALE * log2(e) folded into x_t so attention logits are in log2 domain
    prep_kernel<<<12288, 256, 0, stream>>>((const float4*)x_t, (const float4*)x_s,
                                           (ushort4*)xt_bf, (ushort4*)xs_bf,
                                           0.125f * 1.44269504088896340736f,
                                           W_q, W_kv, W_f, wq_t, wkv_t, wf_t);

    gemm_qkv<<<dim3(24, 32), 256, 0, stream>>>(xt_bf, xs_bf, wq_t, wkv_t, q_ws, k_ws, vt_ws);
    attn_kernel<<<512, 512, 0, stream>>>(q_ws, k_ws, vt_ws, a_ws);
    gemm_fuse<<<dim3(16, 32), 256, 0, stream>>>(a_ws, wf_t, out, b_f);
}